// Round 6
// baseline (2586.724 us; speedup 1.0000x reference)
//
#include <hip/hip_runtime.h>
#include <stdint.h>

#define NN 8192      // nodes
#define FF 512       // feature dim
#define HH 64        // hidden
#define CC 10        // classes
#define EE 262144    // edges
#define NTR 512      // train nodes
#define ALPHA_NS 0.2f

#define HTAB_BITS 19
#define HTAB_CAP (1u << HTAB_BITS)
#define NB 256               // blocks (<= 256 CUs -> co-resident)
#define BT 1024              // threads per block
#define NTH (NB*BT)          // 262144 == EE
#define WPB (BT/64)          // 16 waves per block
#define HB_NB 64             // hist/scatter slice owners
#define HB_EPB (EE/HB_NB)    // 4096 edges per slice
#define ROWS_PB (NN/NB)      // 32 rows per block for Db init

static_assert(NTH == EE, "one thread per edge");

__device__ __forceinline__ float dot4(float4 a, float4 b){
    return a.x*b.x + a.y*b.y + a.z*b.z + a.w*b.w;
}

// sense-reversing grid barrier; bar[0]=cnt (0 at call start), bar[1]=gen
__device__ __forceinline__ void gridbar(uint32_t* bar, int tid){
    __threadfence();               // release this thread's writes
    __syncthreads();
    if (tid == 0){
        uint32_t g = __hip_atomic_load(&bar[1], __ATOMIC_RELAXED, __HIP_MEMORY_SCOPE_AGENT);
        uint32_t a = __hip_atomic_fetch_add(&bar[0], 1u, __ATOMIC_ACQ_REL, __HIP_MEMORY_SCOPE_AGENT);
        if (a == NB - 1u){
            __hip_atomic_store(&bar[0], 0u, __ATOMIC_RELAXED, __HIP_MEMORY_SCOPE_AGENT);
            __hip_atomic_fetch_add(&bar[1], 1u, __ATOMIC_RELEASE, __HIP_MEMORY_SCOPE_AGENT);
        } else {
            while (__hip_atomic_load(&bar[1], __ATOMIC_RELAXED, __HIP_MEMORY_SCOPE_AGENT) == g)
                __builtin_amdgcn_s_sleep(2);
        }
    }
    __syncthreads();
    __threadfence();               // acquire other blocks' writes
}

__global__ __launch_bounds__(BT) void k_mega(
    const float* __restrict__ h, const float* __restrict__ W,
    const float* __restrict__ a, const float* __restrict__ W1,
    const float* __restrict__ feat, const int* __restrict__ ei,
    const int* __restrict__ idx_tr, const int* __restrict__ labels,
    float* __restrict__ out,
    uint32_t* bar, uint32_t* htab, float* e_val,
    uint16_t* hp, float* s1p, uint16_t* pre, uint32_t* tot,
    uint32_t* offs, float* s1, uint32_t* csrc, float* cw,
    float* v01, float* s_src, float* s_dst, float* FW,
    float* Db, float* ua, float* ub)
{
    __shared__ uint32_t sh[NN];        // 32 KB multi-purpose
    __shared__ int   chist[CC];
    __shared__ float cvecl[CC];
    __shared__ uint8_t lmark[ROWS_PB];

    const int tid = threadIdx.x;
    const int b   = blockIdx.x;
    const int gid = b*BT + tid;
    const int wid = tid >> 6, lane = tid & 63;
    const int gw  = b*WPB + wid;       // global wave id, 0..4095

    // ---------------- P0: htab clear + v01 + cvec/Db/ua ----------------
    #pragma unroll
    for (uint32_t i = (uint32_t)gid; i < HTAB_CAP; i += NTH) htab[i] = 0xFFFFFFFFu;

    if (gid < FF){
        int f = gid;
        float a0 = 0.f, a1 = 0.f;
        for (int hh = 0; hh < HH; ++hh){
            float w = W[hh*FF + f];
            a0 += w * a[hh];
            a1 += w * a[HH + hh];
        }
        v01[f] = a0;
        v01[FF + f] = a1;
    }

    if (tid < ROWS_PB) lmark[tid] = 0;
    if (tid < CC) chist[tid] = 0;
    __syncthreads();
    const int rbase = b * ROWS_PB;
    if (tid < NTR){
        int node = idx_tr[tid];
        atomicAdd(&chist[labels[node]], 1);
        unsigned lr = (unsigned)(node - rbase);
        if (lr < (unsigned)ROWS_PB) lmark[lr] = 1;
    }
    __syncthreads();
    if (tid < CC) cvecl[tid] = (float)chist[tid] / (float)NTR;
    __syncthreads();
    if (tid < ROWS_PB*CC){
        int il = tid / CC, c = tid - il*CC;
        int row = rbase + il;
        float v = 0.f;
        if (lmark[il]) v = ((labels[row] == c) ? 1.0f : 0.0f) - cvecl[c];
        Db[row*CC + c] = v;
        ua[row*CC + c] = v;
    }
    gridbar(bar, tid);   // B0

    // ---------------- P1: fused s-dots + FW (2 rows per wave) ----------------
    {
        const float4* v0 = (const float4*)v01;
        const float4* v1 = (const float4*)(v01 + FF);
        #pragma unroll
        for (int rr = 0; rr < 2; ++rr){
            int row = gw + rr*4096;
            const float4* hr = (const float4*)(h + (size_t)row*FF);
            float4 x0 = hr[lane*2], x1 = hr[lane*2+1];
            float a0 = dot4(x0, v0[lane*2]) + dot4(x1, v0[lane*2+1]);
            float a1 = dot4(x0, v1[lane*2]) + dot4(x1, v1[lane*2+1]);
            #pragma unroll
            for (int off = 32; off >= 1; off >>= 1){
                a0 += __shfl_xor(a0, off);
                a1 += __shfl_xor(a1, off);
            }
            if (lane == 0){ s_src[row] = a0; s_dst[row] = a1; }

            const float4* fr = (const float4*)(feat + (size_t)row*FF);
            float4 f0 = fr[lane*2], f1 = fr[lane*2+1];
            float acc[CC];
            #pragma unroll
            for (int c = 0; c < CC; ++c){
                const float4* wr = (const float4*)(W1 + c*FF);
                acc[c] = dot4(f0, wr[lane*2]) + dot4(f1, wr[lane*2+1]);
            }
            #pragma unroll
            for (int c = 0; c < CC; ++c){
                float r = acc[c];
                #pragma unroll
                for (int off = 32; off >= 1; off >>= 1) r += __shfl_xor(r, off);
                acc[c] = r;
            }
            if (lane == 0){
                #pragma unroll
                for (int c = 0; c < CC; ++c) FW[row*CC + c] = acc[c];
            }
        }
    }
    gridbar(bar, tid);   // B1

    // ---------------- P2: dedup via global CAS (one edge per thread) ----------------
    {
        int k = gid;
        int src = ei[k], dst = ei[EE + k];
        uint32_t key = ((uint32_t)src << 13) | (uint32_t)dst;   // 26-bit, != EMPTY
        uint32_t slot = (key * 2654435761u) >> (32 - HTAB_BITS);
        bool owner = false;
        for (uint32_t p = 0; p < HTAB_CAP; ++p){
            uint32_t prev = atomicCAS(&htab[slot], 0xFFFFFFFFu, key);
            if (prev == 0xFFFFFFFFu){ owner = true; break; }
            if (prev == key) break;                   // duplicate pair -> drop
            slot = (slot + 1u) & (HTAB_CAP - 1u);
        }
        if (owner){
            float z = s_src[src] + s_dst[dst];
            z = (z >= 0.f) ? z : ALPHA_NS * z;
            e_val[k] = expf(z);
        } else {
            e_val[k] = -1.0f;
        }
    }
    gridbar(bar, tid);   // B2

    // ---------------- P3: dst-count + src-sum partials (blocks 0..63, 2-pass LDS) ----------------
    if (b < HB_NB){
        for (int i = tid; i < NN; i += BT) sh[i] = 0u;
        __syncthreads();
        int k0 = b * HB_EPB;
        for (int i = tid; i < HB_EPB; i += BT){
            int k = k0 + i;
            if (e_val[k] >= 0.f) atomicAdd(&sh[ei[EE + k]], 1u);
        }
        __syncthreads();
        for (int i = tid; i < NN; i += BT) hp[(size_t)b*NN + i] = (uint16_t)sh[i];
        __syncthreads();
        float* sf = (float*)sh;
        for (int i = tid; i < NN; i += BT) sf[i] = 0.f;
        __syncthreads();
        for (int i = tid; i < HB_EPB; i += BT){
            int k = k0 + i;
            float e = e_val[k];
            if (e >= 0.f) atomicAdd(&sf[ei[k]], e);
        }
        __syncthreads();
        for (int i = tid; i < NN; i += BT) s1p[(size_t)b*NN + i] = sf[i];
    }
    gridbar(bar, tid);   // B3

    // ---------------- P4: per-bin cross-slice prefix + totals + s1 ----------------
    if (gid < NN){
        int bin = gid;
        uint32_t sum = 0;
        #pragma unroll
        for (int bb = 0; bb < HB_NB; ++bb){
            pre[(size_t)bin*HB_NB + bb] = (uint16_t)sum;
            sum += hp[(size_t)bb*NN + bin];
        }
        tot[bin] = sum;
        float fs = 0.f;
        #pragma unroll
        for (int bb = 0; bb < HB_NB; ++bb) fs += s1p[(size_t)bb*NN + bin];
        s1[bin] = fs;
    }
    gridbar(bar, tid);   // B4

    // ---------------- P5: row-offset scan + self-loop entries (block 0) ----------------
    if (b == 0){
        uint32_t local[8];
        uint32_t sum = 0;
        #pragma unroll
        for (int i = 0; i < 8; ++i){
            int idx = tid*8 + i;
            uint32_t v = tot[idx] + (s1[idx] == 0.0f ? 1u : 0u);
            local[i] = v; sum += v;
        }
        sh[tid] = sum;
        __syncthreads();
        for (int off = 1; off < 1024; off <<= 1){
            uint32_t v = (tid >= off) ? sh[tid - off] : 0u;
            __syncthreads();
            sh[tid] += v;
            __syncthreads();
        }
        uint32_t basep = (tid > 0) ? sh[tid-1] : 0u;
        #pragma unroll
        for (int i = 0; i < 8; ++i){
            int idx = tid*8 + i;
            offs[idx] = basep;
            uint32_t v = local[i];
            if (s1[idx] == 0.0f){   // zero-out-degree row -> self-loop at row end
                csrc[basep + v - 1] = (uint32_t)idx;
                cw[basep + v - 1] = 1.0f;
            }
            basep += v;
        }
        if (tid == 1023) offs[NN] = basep;
    }
    gridbar(bar, tid);   // B5

    // ---------------- P6: scatter into CSC (blocks 0..63, LDS ranks) ----------------
    if (b < HB_NB){
        for (int i = tid; i < NN; i += BT) sh[i] = 0u;
        __syncthreads();
        int k0 = b * HB_EPB;
        for (int i = tid; i < HB_EPB; i += BT){
            int k = k0 + i;
            float e = e_val[k];
            if (e >= 0.f){
                int src = ei[k], dst = ei[EE + k];
                uint32_t r = atomicAdd(&sh[dst], 1u);
                uint32_t pos = offs[dst] + (uint32_t)pre[(size_t)dst*HB_NB + b] + r;
                csrc[pos] = (uint32_t)src;
                cw[pos] = e / s1[src];
            }
        }
    }
    gridbar(bar, tid);   // B6

    // ---------------- P7: 9 diffusion steps (2 rows per wave each) ----------------
    {
        float* cur = ua;
        float* nxt = ub;
        for (int s = 2; s <= 10; ++s){
            float* dst = (s == 10) ? out : nxt;
            #pragma unroll
            for (int rr = 0; rr < 2; ++rr){
                int row = gw + rr*4096;
                uint32_t st = offs[row], en = offs[row+1];
                float acc[CC];
                #pragma unroll
                for (int c = 0; c < CC; ++c) acc[c] = 0.f;
                for (uint32_t p = st + lane; p < en; p += 64){
                    uint32_t sr = csrc[p];
                    float w = cw[p];
                    const float2* u2 = (const float2*)(cur + (size_t)sr*CC);
                    #pragma unroll
                    for (int q = 0; q < 5; ++q){
                        float2 v = u2[q];
                        acc[2*q]   += w * v.x;
                        acc[2*q+1] += w * v.y;
                    }
                }
                #pragma unroll
                for (int c = 0; c < CC; ++c){
                    float r = acc[c];
                    #pragma unroll
                    for (int off = 32; off >= 1; off >>= 1) r += __shfl_xor(r, off);
                    acc[c] = r;
                }
                if (lane == 0){
                    const float* db = Db + row*CC;
                    float* o = dst + row*CC;
                    if (s == 7){
                        const float* fw = FW + row*CC;
                        #pragma unroll
                        for (int c = 0; c < CC; ++c) o[c] = acc[c] + db[c] + fw[c];
                    } else {
                        #pragma unroll
                        for (int c = 0; c < CC; ++c) o[c] = acc[c] + db[c];
                    }
                }
            }
            if (s < 10) gridbar(bar, tid);   // B7..B14
            float* tmp = cur; cur = dst; nxt = tmp;
        }
    }
}

extern "C" void kernel_launch(void* const* d_in, const int* in_sizes, int n_in,
                              void* d_out, int out_size, void* d_ws, size_t ws_size,
                              hipStream_t stream){
    const float* h    = (const float*)d_in[0];
    const float* W    = (const float*)d_in[1];
    const float* a    = (const float*)d_in[2];
    const float* W1   = (const float*)d_in[3];
    const float* feat = (const float*)d_in[4];
    const int* ei     = (const int*)d_in[5];
    const int* idx_tr = (const int*)d_in[6];
    const int* labels = (const int*)d_in[7];
    float* out = (float*)d_out;

    char* wsp = (char*)d_ws;
    auto alloc = [&](size_t bytes)->void*{
        void* p = (void*)wsp;
        wsp += (bytes + 255) & ~(size_t)255;
        return p;
    };
    uint32_t* bar    = (uint32_t*)alloc(256);                       // cnt, gen
    uint32_t* htab   = (uint32_t*)alloc((size_t)HTAB_CAP*4);        // 2 MB
    float*    e_val  = (float*)   alloc((size_t)EE*4);              // 1 MB
    uint16_t* hp     = (uint16_t*)alloc((size_t)HB_NB*NN*2);        // 1 MB
    float*    s1p    = (float*)   alloc((size_t)HB_NB*NN*4);        // 2 MB
    uint16_t* pre    = (uint16_t*)alloc((size_t)NN*HB_NB*2);        // 1 MB
    uint32_t* tot    = (uint32_t*)alloc(NN*4);
    uint32_t* offs   = (uint32_t*)alloc((NN+1)*4);
    float*    s1     = (float*)   alloc(NN*4);
    uint32_t* csrc   = (uint32_t*)alloc((size_t)(EE+NN)*4);         // 1.05 MB
    float*    cw     = (float*)   alloc((size_t)(EE+NN)*4);         // 1.05 MB
    float*    v01    = (float*)   alloc(2*FF*4);
    float*    s_src  = (float*)   alloc(NN*4);
    float*    s_dst  = (float*)   alloc(NN*4);
    float*    FW     = (float*)   alloc((size_t)NN*CC*4);
    float*    Db     = (float*)   alloc((size_t)NN*CC*4);
    float*    ua     = (float*)   alloc((size_t)NN*CC*4);
    float*    ub     = (float*)   alloc((size_t)NN*CC*4);

    // barrier state must be zero at call start (ws is poisoned 0xAA initially)
    hipMemsetAsync(bar, 0, 256, stream);

    k_mega<<<NB, BT, 0, stream>>>(h, W, a, W1, feat, ei, idx_tr, labels, out,
                                  bar, htab, e_val, hp, s1p, pre, tot,
                                  offs, s1, csrc, cw, v01, s_src, s_dst, FW,
                                  Db, ua, ub);
}

// Round 7
// 110.373 us; speedup vs baseline: 23.4363x; 23.4363x over previous
//
#include <hip/hip_runtime.h>
#include <stdint.h>

#define NN 8192      // nodes
#define FF 512       // feature dim
#define HH 64        // hidden
#define CC 10        // classes
#define EE 262144    // edges
#define NTR 512      // train nodes
#define ALPHA_NS 0.2f

#define CAP 96u              // slots per dst row (Poisson(32); P(deg>96) ~ e^-38)
#define EMPTY 0xFFFFFFFFu
#define ROWS_PB 32           // rows per k_init block

__device__ __forceinline__ float dot4(float4 a, float4 b){
    return a.x*b.x + a.y*b.y + a.z*b.z + a.w*b.w;
}

// ---------------------------------------------------------------------------
// k_init: per-block independent. Clears row-table slice + s1, computes v01
// redundantly in LDS, then s_src/s_dst/FW for its 32 rows, local cvec, Db.
// ---------------------------------------------------------------------------
__global__ __launch_bounds__(1024) void k_init(
    const float* __restrict__ W, const float* __restrict__ a,
    const float* __restrict__ h, const float* __restrict__ feat,
    const float* __restrict__ W1, const int* __restrict__ idx_tr,
    const int* __restrict__ labels,
    uint32_t* __restrict__ csrc2, float* __restrict__ s1,
    float* __restrict__ s_src, float* __restrict__ s_dst,
    float* __restrict__ FW, float* __restrict__ Db)
{
    __shared__ float v0l[FF];
    __shared__ float v1l[FF];
    __shared__ int chist[CC];
    __shared__ float cvecl[CC];
    __shared__ uint8_t lmark[ROWS_PB];

    const int tid = threadIdx.x;
    const int b   = blockIdx.x;
    const int rbase = b * ROWS_PB;

    // clear this block's slice of the row table (NN*CAP/256 = 3072 slots)
    const uint32_t spb = (NN * CAP) / 256u;
    for (uint32_t i = tid; i < spb; i += 1024) csrc2[(uint32_t)b*spb + i] = EMPTY;
    if (tid < ROWS_PB) s1[rbase + tid] = 0.f;

    // v01 in LDS: threads 0..511 -> v0, 512..1023 -> v1
    {
        int f = tid & (FF-1);
        const float* av = (tid < FF) ? a : (a + HH);
        float acc = 0.f;
        for (int hh = 0; hh < HH; ++hh) acc += W[hh*FF + f] * av[hh];
        if (tid < FF) v0l[f] = acc; else v1l[f] = acc;
    }

    if (tid < ROWS_PB) lmark[tid] = 0;
    if (tid < CC) chist[tid] = 0;
    __syncthreads();
    if (tid < NTR){
        int node = idx_tr[tid];
        atomicAdd(&chist[labels[node]], 1);
        unsigned lr = (unsigned)(node - rbase);
        if (lr < (unsigned)ROWS_PB) lmark[lr] = 1;
    }
    __syncthreads();
    if (tid < CC) cvecl[tid] = (float)chist[tid] / (float)NTR;
    __syncthreads();

    // s-dots + FW: 16 waves x 2 rows
    {
        const int wid = tid >> 6, lane = tid & 63;
        const float4* v0 = (const float4*)v0l;
        const float4* v1 = (const float4*)v1l;
        #pragma unroll
        for (int rr = 0; rr < 2; ++rr){
            int row = rbase + wid*2 + rr;
            const float4* hr = (const float4*)(h + (size_t)row*FF);
            float4 x0 = hr[lane*2], x1 = hr[lane*2+1];
            float a0 = dot4(x0, v0[lane*2]) + dot4(x1, v0[lane*2+1]);
            float a1 = dot4(x0, v1[lane*2]) + dot4(x1, v1[lane*2+1]);
            #pragma unroll
            for (int off = 32; off >= 1; off >>= 1){
                a0 += __shfl_xor(a0, off);
                a1 += __shfl_xor(a1, off);
            }
            if (lane == 0){ s_src[row] = a0; s_dst[row] = a1; }

            const float4* fr = (const float4*)(feat + (size_t)row*FF);
            float4 f0 = fr[lane*2], f1 = fr[lane*2+1];
            float acc[CC];
            #pragma unroll
            for (int c = 0; c < CC; ++c){
                const float4* wr = (const float4*)(W1 + c*FF);
                acc[c] = dot4(f0, wr[lane*2]) + dot4(f1, wr[lane*2+1]);
            }
            #pragma unroll
            for (int c = 0; c < CC; ++c){
                float r = acc[c];
                #pragma unroll
                for (int off = 32; off >= 1; off >>= 1) r += __shfl_xor(r, off);
                acc[c] = r;
            }
            if (lane == 0){
                #pragma unroll
                for (int c = 0; c < CC; ++c) FW[row*CC + c] = acc[c];
            }
        }
    }

    // Db for this block's 32 rows (320 elements)
    if (tid < ROWS_PB*CC){
        int il = tid / CC, c = tid - il*CC;
        int row = rbase + il;
        float v = 0.f;
        if (lmark[il]) v = ((labels[row] == c) ? 1.0f : 0.0f) - cvecl[c];
        Db[row*CC + c] = v;
    }
}

// ---------------------------------------------------------------------------
// k_build: one thread per edge. Dedup + placement in ONE step: open-addressing
// CAS inside the dst row's 96 slots, keyed by src (same src -> same probe
// sequence -> exactly one owner). Owner stores raw e and accumulates s1[src].
// ---------------------------------------------------------------------------
__global__ void k_build(const int* __restrict__ ei, const float* __restrict__ s_src,
                        const float* __restrict__ s_dst,
                        uint32_t* __restrict__ csrc2, float* __restrict__ e2,
                        float* __restrict__ s1)
{
    int k = blockIdx.x*256 + threadIdx.x;
    int src = ei[k], dst = ei[EE + k];
    uint32_t base = (uint32_t)dst * CAP;
    uint32_t p = (uint32_t)(((uint64_t)((uint32_t)src * 2654435761u) * CAP) >> 32);
    float z = s_src[src] + s_dst[dst];
    z = (z >= 0.f) ? z : ALPHA_NS * z;
    float e = expf(z);
    for (uint32_t it = 0; it < CAP; ++it){
        uint32_t prev = atomicCAS(&csrc2[base + p], EMPTY, (uint32_t)src);
        if (prev == EMPTY){
            e2[base + p] = e;
            atomicAdd(&s1[src], e);
            break;
        }
        if (prev == (uint32_t)src) break;   // duplicate (same value) -> drop
        p = (p + 1u == CAP) ? 0u : p + 1u;
    }
}

// ---------------------------------------------------------------------------
// k_fixup: one wave per row. Ballot-compact the row's slots in place, insert
// self-loop for zero-out-degree rows, write cnt, and uhat1 = Db/s1.
// ---------------------------------------------------------------------------
__global__ __launch_bounds__(1024) void k_fixup(
    uint32_t* __restrict__ csrc2, float* __restrict__ e2,
    float* __restrict__ s1, uint32_t* __restrict__ cnt,
    const float* __restrict__ Db, float* __restrict__ uhA)
{
    const int tid = threadIdx.x;
    const int wid = tid >> 6, lane = tid & 63;
    const int row = blockIdx.x*16 + wid;     // 512 blocks x 16 waves
    const uint32_t base = (uint32_t)row * CAP;

    uint32_t c0 = csrc2[base + lane];
    uint32_t c1 = (lane < (int)(CAP - 64u)) ? csrc2[base + 64 + lane] : EMPTY;
    float    e0 = e2[base + lane];
    float    e1 = (lane < (int)(CAP - 64u)) ? e2[base + 64 + lane] : 0.f;

    uint64_t m0 = __ballot(c0 != EMPTY);
    uint64_t m1 = __ballot((lane < (int)(CAP - 64u)) && c1 != EMPTY);
    uint64_t below = (lane == 63) ? ~0ull >> 1 : ((1ull << lane) - 1ull);
    // (1ull<<63)-1 is fine too; avoid UB paranoia
    below = ((1ull << lane) - 1ull);
    uint32_t t0   = (uint32_t)__popcll(m0);
    uint32_t pos0 = (uint32_t)__popcll(m0 & below);
    uint32_t pos1 = t0 + (uint32_t)__popcll(m1 & below);
    uint32_t total = t0 + (uint32_t)__popcll(m1);

    __syncthreads();   // all reads of this block's rows complete before any write

    if (c0 != EMPTY){ csrc2[base + pos0] = c0; e2[base + pos0] = e0; }
    if (lane < (int)(CAP - 64u) && c1 != EMPTY){ csrc2[base + pos1] = c1; e2[base + pos1] = e1; }

    float s1v = 0.f;
    if (lane == 0){
        s1v = s1[row];
        if (s1v == 0.f){                    // zero out-degree -> self loop, w=1
            csrc2[base + total] = (uint32_t)row;
            e2[base + total] = 1.0f;
            total += 1u;
            s1[row] = 1.0f;
            s1v = 1.0f;
        }
        cnt[row] = total;
    }
    s1v = __shfl(s1v, 0);
    if (lane < CC) uhA[row*CC + lane] = Db[row*CC + lane] / s1v;
}

// ---------------------------------------------------------------------------
// k_spmv: 2 rows per wave (32-lane halves). Raw-e gather of uhat, then
// uhat_out = (sum + Db (+FW)) / s1[row]; final step writes out unnormalized.
// ---------------------------------------------------------------------------
__global__ __launch_bounds__(1024) void k_spmv(
    const uint32_t* __restrict__ cnt, const uint32_t* __restrict__ csrc2,
    const float* __restrict__ e2, const float* __restrict__ uh_in,
    const float* __restrict__ Db, const float* __restrict__ FW,
    const float* __restrict__ s1, float* __restrict__ uout,
    int add_fw, int final_step)
{
    const int tid = threadIdx.x;
    const int wid = tid >> 6, lane = tid & 63;
    const int sub = lane >> 5, l32 = lane & 31;
    const int row = (blockIdx.x*16 + wid)*2 + sub;   // 256 blocks
    const uint32_t base = (uint32_t)row * CAP;
    const uint32_t n = cnt[row];

    float acc[CC];
    #pragma unroll
    for (int c = 0; c < CC; ++c) acc[c] = 0.f;
    for (uint32_t p = (uint32_t)l32; p < n; p += 32u){
        uint32_t sr = csrc2[base + p];
        float w = e2[base + p];
        const float2* u2 = (const float2*)(uh_in + (size_t)sr*CC);
        #pragma unroll
        for (int q = 0; q < 5; ++q){
            float2 v = u2[q];
            acc[2*q]   += w * v.x;
            acc[2*q+1] += w * v.y;
        }
    }
    #pragma unroll
    for (int c = 0; c < CC; ++c){
        float r = acc[c];
        #pragma unroll
        for (int off = 16; off >= 1; off >>= 1) r += __shfl_xor(r, off);
        acc[c] = r;
    }
    if (l32 == 0){
        const float* db = Db + row*CC;
        float* o = uout + row*CC;
        float t[CC];
        #pragma unroll
        for (int c = 0; c < CC; ++c) t[c] = acc[c] + db[c];
        if (add_fw){
            const float* fw = FW + row*CC;
            #pragma unroll
            for (int c = 0; c < CC; ++c) t[c] += fw[c];
        }
        if (final_step){
            #pragma unroll
            for (int c = 0; c < CC; ++c) o[c] = t[c];
        } else {
            float inv = 1.0f / s1[row];
            #pragma unroll
            for (int c = 0; c < CC; ++c) o[c] = t[c] * inv;
        }
    }
}

extern "C" void kernel_launch(void* const* d_in, const int* in_sizes, int n_in,
                              void* d_out, int out_size, void* d_ws, size_t ws_size,
                              hipStream_t stream){
    const float* h    = (const float*)d_in[0];
    const float* W    = (const float*)d_in[1];
    const float* a    = (const float*)d_in[2];
    const float* W1   = (const float*)d_in[3];
    const float* feat = (const float*)d_in[4];
    const int* ei     = (const int*)d_in[5];
    const int* idx_tr = (const int*)d_in[6];
    const int* labels = (const int*)d_in[7];
    float* out = (float*)d_out;

    char* wsp = (char*)d_ws;
    auto alloc = [&](size_t bytes)->void*{
        void* p = (void*)wsp;
        wsp += (bytes + 255) & ~(size_t)255;
        return p;
    };
    uint32_t* csrc2 = (uint32_t*)alloc((size_t)NN*CAP*4);   // 3 MB
    float*    e2    = (float*)   alloc((size_t)NN*CAP*4);   // 3 MB
    float*    s1    = (float*)   alloc(NN*4);
    uint32_t* cnt   = (uint32_t*)alloc(NN*4);
    float*    s_src = (float*)   alloc(NN*4);
    float*    s_dst = (float*)   alloc(NN*4);
    float*    FW    = (float*)   alloc((size_t)NN*CC*4);
    float*    Db    = (float*)   alloc((size_t)NN*CC*4);
    float*    uhA   = (float*)   alloc((size_t)NN*CC*4);
    float*    uhB   = (float*)   alloc((size_t)NN*CC*4);

    k_init <<<256, 1024, 0, stream>>>(W, a, h, feat, W1, idx_tr, labels,
                                      csrc2, s1, s_src, s_dst, FW, Db);
    k_build<<<EE/256, 256, 0, stream>>>(ei, s_src, s_dst, csrc2, e2, s1);
    k_fixup<<<NN/16, 1024, 0, stream>>>(csrc2, e2, s1, cnt, Db, uhA);

    float* cur = uhA;
    float* nxt = uhB;
    for (int t = 2; t <= 10; ++t){
        float* dst = (t == 10) ? out : nxt;
        k_spmv<<<NN/32, 1024, 0, stream>>>(cnt, csrc2, e2, cur, Db, FW, s1, dst,
                                           (t == 7) ? 1 : 0, (t == 10) ? 1 : 0);
        float* tmp = cur; cur = dst; nxt = tmp;
    }
}